// Round 5
// baseline (262.920 us; speedup 1.0000x reference)
//
#include <hip/hip_runtime.h>

typedef _Float16 f16;
typedef __fp16 h16x2 __attribute__((ext_vector_type(2)));
typedef _Float16 f16x8 __attribute__((ext_vector_type(8)));
typedef float f32x4 __attribute__((ext_vector_type(4)));

#define MFMA16(a,b,c) __builtin_amdgcn_mfma_f32_16x16x32_f16((a),(b),(c),0,0,0)

__device__ __forceinline__ void gload16(const void* g, void* l) {
  __builtin_amdgcn_global_load_lds(
      (const __attribute__((address_space(1))) void*)g,
      (__attribute__((address_space(3))) void*)l, 16, 0, 0);
}

// swizzled f16 offset within a [rows][32 k] tile; c = 8-f16 chunk (0..3)
__device__ __forceinline__ int swz(int r, int c) {
  return r * 32 + ((c ^ (r & 3)) << 3);
}

// RTZ split (fallback hot loop)
__device__ __forceinline__ void split8z(const f32x4 v0, const f32x4 v1,
                                        f16x8& hv, f16x8& lv) {
  h16x2 h01 = __builtin_amdgcn_cvt_pkrtz(v0[0], v0[1]);
  h16x2 h23 = __builtin_amdgcn_cvt_pkrtz(v0[2], v0[3]);
  h16x2 h45 = __builtin_amdgcn_cvt_pkrtz(v1[0], v1[1]);
  h16x2 h67 = __builtin_amdgcn_cvt_pkrtz(v1[2], v1[3]);
  hv[0] = (f16)h01[0]; hv[1] = (f16)h01[1]; hv[2] = (f16)h23[0]; hv[3] = (f16)h23[1];
  hv[4] = (f16)h45[0]; hv[5] = (f16)h45[1]; hv[6] = (f16)h67[0]; hv[7] = (f16)h67[1];
  h16x2 l01 = __builtin_amdgcn_cvt_pkrtz(v0[0] - (float)h01[0], v0[1] - (float)h01[1]);
  h16x2 l23 = __builtin_amdgcn_cvt_pkrtz(v0[2] - (float)h23[0], v0[3] - (float)h23[1]);
  h16x2 l45 = __builtin_amdgcn_cvt_pkrtz(v1[0] - (float)h45[0], v1[1] - (float)h45[1]);
  h16x2 l67 = __builtin_amdgcn_cvt_pkrtz(v1[2] - (float)h67[0], v1[3] - (float)h67[1]);
  lv[0] = (f16)l01[0]; lv[1] = (f16)l01[1]; lv[2] = (f16)l23[0]; lv[3] = (f16)l23[1];
  lv[4] = (f16)l45[0]; lv[5] = (f16)l45[1]; lv[6] = (f16)l67[0]; lv[7] = (f16)l67[1];
}

// RTN split (prep paths — half the residual of RTZ)
__device__ __forceinline__ void split8n(const f32x4 v0, const f32x4 v1,
                                        f16x8& hv, f16x8& lv) {
#pragma unroll
  for (int j = 0; j < 4; ++j) {
    f16 h0 = (f16)v0[j]; hv[j] = h0; lv[j] = (f16)(v0[j] - (float)h0);
    f16 h1 = (f16)v1[j]; hv[j + 4] = h1; lv[j + 4] = (f16)(v1[j] - (float)h1);
  }
}

// ---------- prep: f32 in[R][C] -> tiled+swizzled fp16 hi/lo tiles ----------
// tile rows TR = 1<<trShift; tileIdx = (n/TR)*(R/32) + k/32
__global__ __launch_bounds__(256) void k_prep(const float* __restrict__ in,
                                              f16* __restrict__ oh, f16* __restrict__ ol,
                                              int R, int C, int trShift) {
  __shared__ float t[64][65];
  int c0 = blockIdx.x * 64, r0 = blockIdx.y * 64;
  int tid = threadIdx.x;
#pragma unroll
  for (int i = 0; i < 16; ++i) {
    int idx = tid + i * 256;
    int r = idx >> 6, c = idx & 63;
    t[r][c] = in[(size_t)(r0 + r) * C + (c0 + c)];
  }
  __syncthreads();
  int ktiles = R >> 5;
  int TRm1 = (1 << trShift) - 1;
#pragma unroll
  for (int w = 0; w < 2; ++w) {
    int idx = tid + w * 256;
    int nn = idx >> 3, cc8 = idx & 7;
    f32x4 v0, v1;
#pragma unroll
    for (int j = 0; j < 4; ++j) v0[j] = t[cc8 * 8 + j][nn];
#pragma unroll
    for (int j = 0; j < 4; ++j) v1[j] = t[cc8 * 8 + 4 + j][nn];
    f16x8 hv, lv;
    split8n(v0, v1, hv, lv);
    int gn = c0 + nn, gk = r0 + cc8 * 8;
    size_t tileIdx = (size_t)(gn >> trShift) * ktiles + (gk >> 5);
    size_t off = (tileIdx << (trShift + 5)) + ((size_t)(gn & TRm1) << 5) +
                 (((cc8 & 3) ^ (gn & 3)) << 3);
    *(f16x8*)&oh[off] = hv;
    *(f16x8*)&ol[off] = lv;
  }
}

// ---------- xprep: X f32 -> tiled+swizzled fp16 hi/lo (TR=64) + mask ----------
__global__ __launch_bounds__(256) void k_xprep(const float* __restrict__ X,
                                               f16* __restrict__ Xh, f16* __restrict__ Xl,
                                               unsigned short* __restrict__ mb2) {
  int m0 = blockIdx.x * 64, kb0 = blockIdx.y * 64;
  int tid = threadIdx.x;
  int r = tid >> 2, c0 = (tid & 3) * 16;
  const float* p = X + (size_t)(m0 + r) * 4096 + kb0 + c0;
  f32x4 a0 = *(const f32x4*)p, a1 = *(const f32x4*)(p + 4);
  f32x4 a2 = *(const f32x4*)(p + 8), a3 = *(const f32x4*)(p + 12);
  f16x8 h0, l0, h1, l1;
  split8n(a0, a1, h0, l0);
  split8n(a2, a3, h1, l1);
  int gk = kb0 + c0;
  int kt = gk >> 5, cc = (gk & 31) >> 3;
  size_t tile = (size_t)blockIdx.x * 128 + kt;
  size_t o0 = tile * 2048 + swz(r, cc);
  size_t o1 = tile * 2048 + swz(r, cc + 1);
  *(f16x8*)&Xh[o0] = h0; *(f16x8*)&Xh[o1] = h1;
  *(f16x8*)&Xl[o0] = l0; *(f16x8*)&Xl[o1] = l1;
  unsigned m = 0;
#pragma unroll
  for (int j = 0; j < 4; ++j) {
    if (a0[j] != 0.f) m |= 1u << j;
    if (a1[j] != 0.f) m |= 1u << (4 + j);
    if (a2[j] != 0.f) m |= 1u << (8 + j);
    if (a3[j] != 0.f) m |= 1u << (12 + j);
  }
  mb2[((size_t)(m0 + r) * 512 + (gk >> 3)) >> 1] = (unsigned short)m;
}

// ---------- GEMM1 pipelined: all-gload staging, counted vmcnt ----------
// BM=64, BN=128, BK=32; A and B both 3-buffered, distance-2 prefetch
__global__ __launch_bounds__(256, 2) void k_gemm1p(
    const f16* __restrict__ Xh, const f16* __restrict__ Xl,
    const f16* __restrict__ Bht, const f16* __restrict__ Blt,
    float* __restrict__ partials) {
  __shared__ f16 smA[3][4096];   // [buf][Ah 0..2048 | Al 2048..4096]
  __shared__ f16 smB[3][8192];   // [buf][Bh 0..4096 | Bl 4096..8192]
  int bx = blockIdx.x, nb = blockIdx.y, kc = blockIdx.z;
  int tid = threadIdx.x;
  int wv = tid >> 6, ln = tid & 63, lr = ln & 15, lg = ln >> 4;
  int wr = wv >> 1, wc = wv & 1;
  const int NS = 64;
  size_t a0 = ((size_t)bx * 128 + (size_t)kc * 64) * 2048;
  size_t b0 = ((size_t)nb * 128 + (size_t)kc * 64) * 4096;

  auto issueTile = [&](int s, int buf) {
    const f16* ah = Xh + a0 + (size_t)s * 2048 + (size_t)tid * 8;
    const f16* al = Xl + a0 + (size_t)s * 2048 + (size_t)tid * 8;
    gload16(ah, &smA[buf][wv * 512]);
    gload16(al, &smA[buf][2048 + wv * 512]);
    const f16* bh = Bht + b0 + (size_t)s * 4096 + (size_t)tid * 8;
    const f16* bl = Blt + b0 + (size_t)s * 4096 + (size_t)tid * 8;
    gload16(bh, &smB[buf][wv * 512]);
    gload16(bh + 2048, &smB[buf][2048 + wv * 512]);
    gload16(bl, &smB[buf][4096 + wv * 512]);
    gload16(bl + 2048, &smB[buf][6144 + wv * 512]);
  };

  f32x4 acc[2][4] = {};

  // prologue: tiles 0 and 1 in flight (12 loads); complete tile 0, keep tile 1
  issueTile(0, 0);
  issueTile(1, 1);
  asm volatile("s_waitcnt vmcnt(6)" ::: "memory");
  __builtin_amdgcn_s_barrier();

  int cb = 0;
  for (int s = 0; s < NS; ++s) {
    if (s + 2 < NS) {
      int pb = cb + 2; if (pb >= 3) pb -= 3;
      issueTile(s + 2, pb);
    }
    const f16* ab = &smA[cb][0];
    const f16* bb = &smB[cb][0];
    f16x8 fah[2], fal[2], fbh[4], fbl[4];
#pragma unroll
    for (int fi = 0; fi < 2; ++fi) {
      int r = wr * 32 + fi * 16 + lr;
      fah[fi] = *(const f16x8*)(ab + swz(r, lg));
      fal[fi] = *(const f16x8*)(ab + 2048 + swz(r, lg));
    }
#pragma unroll
    for (int fj = 0; fj < 4; ++fj) {
      int c = wc * 64 + fj * 16 + lr;
      fbh[fj] = *(const f16x8*)(bb + swz(c, lg));
      fbl[fj] = *(const f16x8*)(bb + 4096 + swz(c, lg));
    }
#pragma unroll
    for (int fi = 0; fi < 2; ++fi)
#pragma unroll
      for (int fj = 0; fj < 4; ++fj) {
        acc[fi][fj] = MFMA16(fah[fi], fbh[fj], acc[fi][fj]);
        acc[fi][fj] = MFMA16(fah[fi], fbl[fj], acc[fi][fj]);
        acc[fi][fj] = MFMA16(fal[fi], fbh[fj], acc[fi][fj]);
      }
    if (s + 2 < NS)
      asm volatile("s_waitcnt vmcnt(6)" ::: "memory");  // complete s+1, keep s+2 flying
    else
      asm volatile("s_waitcnt vmcnt(0)" ::: "memory");
    __builtin_amdgcn_s_barrier();
    cb = cb + 1; if (cb >= 3) cb -= 3;
  }

  float* pout = partials + (size_t)kc * 8192 * 256;
#pragma unroll
  for (int fi = 0; fi < 2; ++fi)
#pragma unroll
    for (int fj = 0; fj < 4; ++fj)
#pragma unroll
      for (int r = 0; r < 4; ++r) {
        int row = bx * 64 + wr * 32 + fi * 16 + lg * 4 + r;
        int col = nb * 128 + wc * 64 + fj * 16 + lr;
        pout[(size_t)row * 256 + col] = acc[fi][fj][r];
      }
}

// ---------- GEMM1 fallback (R3 reg-staged) ----------
__global__ __launch_bounds__(256, 4) void k_gemm1f(
    const float* __restrict__ X, const f16* __restrict__ Bht,
    const f16* __restrict__ Blt, unsigned char* __restrict__ mb,
    float* __restrict__ partials) {
  __shared__ f16 sm[2][4][64 * 32];
  int m0 = blockIdx.x * 64, nb = blockIdx.y, kc = blockIdx.z;
  int tid = threadIdx.x;
  int wv = tid >> 6, ln = tid & 63, lr = ln & 15, lg = ln >> 4;
  int wr = wv >> 1, wc = wv & 1;
  int ar = tid >> 2, ac = tid & 3;
  const int NS = 64;
  int kbase = kc * 2048;
  const float* xrow = X + (size_t)(m0 + ar) * 4096 + kbase + ac * 8;
  size_t btile0 = ((size_t)nb * 128 + (size_t)kc * 64) * 2048;
  bool domask = (nb == 0);
  f32x4 acc[2][2] = {};

  {
    gload16(Bht + btile0 + (size_t)tid * 8, &sm[0][2][wv * 512]);
    gload16(Blt + btile0 + (size_t)tid * 8, &sm[0][3][wv * 512]);
    f32x4 v0 = *(const f32x4*)(xrow);
    f32x4 v1 = *(const f32x4*)(xrow + 4);
    f16x8 hv, lv;
    split8z(v0, v1, hv, lv);
    *(f16x8*)&sm[0][0][swz(ar, ac)] = hv;
    *(f16x8*)&sm[0][1][swz(ar, ac)] = lv;
    if (domask) {
      unsigned m = 0;
      if (v0[0] != 0.f) m |= 1u;
      if (v0[1] != 0.f) m |= 2u;
      if (v0[2] != 0.f) m |= 4u;
      if (v0[3] != 0.f) m |= 8u;
      if (v1[0] != 0.f) m |= 16u;
      if (v1[1] != 0.f) m |= 32u;
      if (v1[2] != 0.f) m |= 64u;
      if (v1[3] != 0.f) m |= 128u;
      mb[(size_t)(m0 + ar) * 512 + (kbase >> 3) + ac] = (unsigned char)m;
    }
  }
  __syncthreads();

  int cur = 0;
  for (int s = 0; s < NS; ++s) {
    bool more = (s + 1) < NS;
    f32x4 v0, v1;
    if (more) {
      size_t bt = btile0 + (size_t)(s + 1) * 2048;
      gload16(Bht + bt + (size_t)tid * 8, &sm[cur ^ 1][2][wv * 512]);
      gload16(Blt + bt + (size_t)tid * 8, &sm[cur ^ 1][3][wv * 512]);
      v0 = *(const f32x4*)(xrow + (s + 1) * 32);
      v1 = *(const f32x4*)(xrow + (s + 1) * 32 + 4);
    }
    f16x8 fah[2], fal[2], fbh[2], fbl[2];
#pragma unroll
    for (int fi = 0; fi < 2; ++fi) {
      int r = wr * 32 + fi * 16 + lr;
      fah[fi] = *(const f16x8*)&sm[cur][0][swz(r, lg)];
      fal[fi] = *(const f16x8*)&sm[cur][1][swz(r, lg)];
    }
#pragma unroll
    for (int fj = 0; fj < 2; ++fj) {
      int c = wc * 32 + fj * 16 + lr;
      fbh[fj] = *(const f16x8*)&sm[cur][2][swz(c, lg)];
      fbl[fj] = *(const f16x8*)&sm[cur][3][swz(c, lg)];
    }
#pragma unroll
    for (int fi = 0; fi < 2; ++fi)
#pragma unroll
      for (int fj = 0; fj < 2; ++fj) {
        acc[fi][fj] = MFMA16(fah[fi], fbh[fj], acc[fi][fj]);
        acc[fi][fj] = MFMA16(fah[fi], fbl[fj], acc[fi][fj]);
        acc[fi][fj] = MFMA16(fal[fi], fbh[fj], acc[fi][fj]);
      }
    if (more) {
      f16x8 hv, lv;
      split8z(v0, v1, hv, lv);
      *(f16x8*)&sm[cur ^ 1][0][swz(ar, ac)] = hv;
      *(f16x8*)&sm[cur ^ 1][1][swz(ar, ac)] = lv;
      if (domask) {
        unsigned m = 0;
        if (v0[0] != 0.f) m |= 1u;
        if (v0[1] != 0.f) m |= 2u;
        if (v0[2] != 0.f) m |= 4u;
        if (v0[3] != 0.f) m |= 8u;
        if (v1[0] != 0.f) m |= 16u;
        if (v1[1] != 0.f) m |= 32u;
        if (v1[2] != 0.f) m |= 64u;
        if (v1[3] != 0.f) m |= 128u;
        mb[(size_t)(m0 + ar) * 512 + ((kbase + (s + 1) * 32) >> 3) + ac] =
            (unsigned char)m;
      }
    }
    __syncthreads();
    cur ^= 1;
  }

  float* pout = partials + (size_t)kc * 8192 * 256;
#pragma unroll
  for (int fi = 0; fi < 2; ++fi)
#pragma unroll
    for (int fj = 0; fj < 2; ++fj)
#pragma unroll
      for (int r = 0; r < 4; ++r) {
        int row = m0 + wr * 32 + fi * 16 + lg * 4 + r;
        int col = nb * 64 + wc * 32 + fj * 16 + lr;
        pout[(size_t)row * 256 + col] = acc[fi][fj][r];
      }
}

// ---------- reduce split-K + bias + relu + split -> tiled H hi/lo ----------
__global__ __launch_bounds__(256) void k_hsplit(const float* __restrict__ p,
                                                const float* __restrict__ b1,
                                                f16* __restrict__ Hh,
                                                f16* __restrict__ Hl) {
  int g = blockIdx.x * 256 + threadIdx.x;
  int r = g >> 5, c = g & 31;
  const float* p0 = p + (size_t)r * 256 + c * 8;
  const float* p1 = p0 + (size_t)8192 * 256;
  f32x4 a0 = *(const f32x4*)p0, a1 = *(const f32x4*)(p0 + 4);
  f32x4 d0 = *(const f32x4*)p1, d1 = *(const f32x4*)(p1 + 4);
  f32x4 bb0 = *(const f32x4*)(b1 + c * 8), bb1 = *(const f32x4*)(b1 + c * 8 + 4);
  f32x4 v0, v1;
#pragma unroll
  for (int j = 0; j < 4; ++j) {
    float v = a0[j] + d0[j] + bb0[j];
    v0[j] = v > 0.f ? v : 0.f;
    float w = a1[j] + d1[j] + bb1[j];
    v1[j] = w > 0.f ? w : 0.f;
  }
  f16x8 hv, lv;
  split8n(v0, v1, hv, lv);
  size_t tileIdx = (size_t)(r >> 6) * 8 + (c >> 2);
  size_t off = tileIdx * 2048 + swz(r & 63, c & 3);
  *(f16x8*)&Hh[off] = hv;
  *(f16x8*)&Hl[off] = lv;
}

// ---------- GEMM2: F = H @ W2 + b2, masked store + per-tile row sums ----------
template <bool F16OUT>
__global__ __launch_bounds__(256, 4) void k_gemm2(
    const f16* __restrict__ At_h, const f16* __restrict__ At_l,
    const f16* __restrict__ Bt_h, const f16* __restrict__ Bt_l,
    const float* __restrict__ b2, const unsigned* __restrict__ maskw,
    float* __restrict__ out, f16* __restrict__ fout,
    float* __restrict__ partials) {
  __shared__ f16 sm[2][4][64 * 32];
  __shared__ unsigned mlds[64][2];
  __shared__ float rsum[64][2];
  int m0 = blockIdx.x * 64, n0 = blockIdx.y * 64;
  int tid = threadIdx.x;
  int wv = tid >> 6, ln = tid & 63, lr = ln & 15, lg = ln >> 4;
  int wr = wv >> 1, wc = wv & 1;
  if (tid < 128) {
    int r = tid >> 1, w = tid & 1;
    mlds[r][w] = maskw[(size_t)(m0 + r) * 128 + (n0 >> 5) + w];
  }
  size_t atile0 = (size_t)blockIdx.x * 8 * 2048;
  size_t btile0 = (size_t)blockIdx.y * 8 * 2048;
  f32x4 acc[2][2] = {};

  gload16(At_h + atile0 + (size_t)tid * 8, &sm[0][0][wv * 512]);
  gload16(At_l + atile0 + (size_t)tid * 8, &sm[0][1][wv * 512]);
  gload16(Bt_h + btile0 + (size_t)tid * 8, &sm[0][2][wv * 512]);
  gload16(Bt_l + btile0 + (size_t)tid * 8, &sm[0][3][wv * 512]);
  __syncthreads();

  int cur = 0;
  for (int s = 0; s < 8; ++s) {
    bool more = (s + 1) < 8;
    if (more) {
      size_t at = atile0 + (size_t)(s + 1) * 2048;
      size_t bt = btile0 + (size_t)(s + 1) * 2048;
      gload16(At_h + at + (size_t)tid * 8, &sm[cur ^ 1][0][wv * 512]);
      gload16(At_l + at + (size_t)tid * 8, &sm[cur ^ 1][1][wv * 512]);
      gload16(Bt_h + bt + (size_t)tid * 8, &sm[cur ^ 1][2][wv * 512]);
      gload16(Bt_l + bt + (size_t)tid * 8, &sm[cur ^ 1][3][wv * 512]);
    }
    f16x8 fah[2], fal[2], fbh[2], fbl[2];
#pragma unroll
    for (int fi = 0; fi < 2; ++fi) {
      int r = wr * 32 + fi * 16 + lr;
      fah[fi] = *(const f16x8*)&sm[cur][0][swz(r, lg)];
      fal[fi] = *(const f16x8*)&sm[cur][1][swz(r, lg)];
    }
#pragma unroll
    for (int fj = 0; fj < 2; ++fj) {
      int c = wc * 32 + fj * 16 + lr;
      fbh[fj] = *(const f16x8*)&sm[cur][2][swz(c, lg)];
      fbl[fj] = *(const f16x8*)&sm[cur][3][swz(c, lg)];
    }
#pragma unroll
    for (int fi = 0; fi < 2; ++fi)
#pragma unroll
      for (int fj = 0; fj < 2; ++fj) {
        acc[fi][fj] = MFMA16(fah[fi], fbh[fj], acc[fi][fj]);
        acc[fi][fj] = MFMA16(fah[fi], fbl[fj], acc[fi][fj]);
        acc[fi][fj] = MFMA16(fal[fi], fbh[fj], acc[fi][fj]);
      }
    __syncthreads();
    cur ^= 1;
  }

  float rp[2][4] = {};
#pragma unroll
  for (int fi = 0; fi < 2; ++fi)
#pragma unroll
    for (int fj = 0; fj < 2; ++fj)
#pragma unroll
      for (int r = 0; r < 4; ++r) {
        int row = wr * 32 + fi * 16 + lg * 4 + r;
        int col = wc * 32 + fj * 16 + lr;
        float v = acc[fi][fj][r] + b2[n0 + col];
        unsigned wd = mlds[row][col >> 5];
        float mv = ((wd >> (col & 31)) & 1u) ? v : 0.f;
        if (F16OUT)
          fout[(size_t)(m0 + row) * 4096 + (n0 + col)] = (f16)mv;
        else
          out[(size_t)(m0 + row) * 4096 + (n0 + col)] = mv;
        rp[fi][r] += mv;
      }
#pragma unroll
  for (int fi = 0; fi < 2; ++fi)
#pragma unroll
    for (int r = 0; r < 4; ++r) {
      float s = rp[fi][r];
      s += __shfl_xor(s, 1);
      s += __shfl_xor(s, 2);
      s += __shfl_xor(s, 4);
      s += __shfl_xor(s, 8);
      if (lr == 0) rsum[wr * 32 + fi * 16 + lg * 4 + r][wc] = s;
    }
  __syncthreads();
  if (tid < 64)
    partials[(size_t)(m0 + tid) * 64 + blockIdx.y] = rsum[tid][0] + rsum[tid][1];
}

// ---------- per-row inverse of masked sum ----------
__global__ __launch_bounds__(256) void k_rowinv(const float* __restrict__ partials,
                                                float* __restrict__ inv) {
  int r = blockIdx.x * 256 + threadIdx.x;
  if (r < 8192) {
    float s = 0.f;
#pragma unroll 4
    for (int i = 0; i < 64; ++i) s += partials[(size_t)r * 64 + i];
    float ss = (s == 0.f) ? 1.f : s;
    inv[r] = 1.f / ss;
  }
}

// ---------- scale: f16 f * inv -> f32 out ----------
__global__ __launch_bounds__(256) void k_scale16(const f16* __restrict__ f,
                                                 const float* __restrict__ inv,
                                                 float* __restrict__ out) {
  int v = blockIdx.x * 256 + threadIdx.x;
  float iv = inv[v >> 9];
  f16x8 d = *(const f16x8*)(f + (size_t)v * 8);
  f32x4 o0, o1;
#pragma unroll
  for (int j = 0; j < 4; ++j) {
    o0[j] = (float)d[j] * iv;
    o1[j] = (float)d[4 + j] * iv;
  }
  *(f32x4*)(out + (size_t)v * 8) = o0;
  *(f32x4*)(out + (size_t)v * 8 + 4) = o1;
}

// ---------- scale rows in place (fallback) ----------
__global__ __launch_bounds__(256) void k_scale(float* __restrict__ out,
                                               const float* __restrict__ inv) {
  int v = blockIdx.x * 256 + threadIdx.x;
  float iv = inv[v >> 10];
  f32x4* p = (f32x4*)out;
  f32x4 d = p[v];
  d[0] *= iv; d[1] *= iv; d[2] *= iv; d[3] *= iv;
  p[v] = d;
}

extern "C" void kernel_launch(void* const* d_in, const int* in_sizes, int n_in,
                              void* d_out, int out_size, void* d_ws, size_t ws_size,
                              hipStream_t stream) {
  const float* x  = (const float*)d_in[0];
  const float* W1 = (const float*)d_in[1];
  const float* b1 = (const float*)d_in[2];
  const float* W2 = (const float*)d_in[3];
  const float* b2 = (const float*)d_in[4];
  float* out = (float*)d_out;
  char* ws = (char*)d_ws;

  const size_t MB = (size_t)1 << 20;
  if (ws_size >= 168 * MB) {
    // ---- pipelined path ----
    f16* W1t_h = (f16*)(ws + 0 * MB);
    f16* W1t_l = (f16*)(ws + 2 * MB);
    f16* W2t_h = (f16*)(ws + 4 * MB);
    f16* W2t_l = (f16*)(ws + 6 * MB);
    f16* Xh    = (f16*)(ws + 8 * MB);    // 64 MB
    f16* Xl    = (f16*)(ws + 72 * MB);   // 64 MB
    f16* Hh    = (f16*)(ws + 136 * MB);  // 4 MB
    f16* Hl    = (f16*)(ws + 140 * MB);  // 4 MB
    unsigned char* mb = (unsigned char*)(ws + 144 * MB);  // 4 MB
    float* part1 = (float*)(ws + 148 * MB);  // 16 MB
    float* part2 = (float*)(ws + 164 * MB);  // 2 MB
    float* inv_s = (float*)(ws + 166 * MB);  // 32 KB
    f16* fbuf = Xh;  // 64 MB, X dead after gemm1

    k_prep<<<dim3(4, 64), 256, 0, stream>>>(W1, W1t_h, W1t_l, 4096, 256, 7);
    k_prep<<<dim3(64, 4), 256, 0, stream>>>(W2, W2t_h, W2t_l, 256, 4096, 6);
    k_xprep<<<dim3(128, 64), 256, 0, stream>>>(x, Xh, Xl, (unsigned short*)mb);
    k_gemm1p<<<dim3(128, 2, 2), 256, 0, stream>>>(Xh, Xl, W1t_h, W1t_l, part1);
    k_hsplit<<<1024, 256, 0, stream>>>(part1, b1, Hh, Hl);
    k_gemm2<true><<<dim3(128, 64), 256, 0, stream>>>(
        Hh, Hl, W2t_h, W2t_l, b2, (const unsigned*)mb, out, fbuf, part2);
    k_rowinv<<<32, 256, 0, stream>>>(part2, inv_s);
    k_scale16<<<16384, 256, 0, stream>>>(fbuf, inv_s, out);
  } else {
    // ---- fallback: R3 path ----
    f16* W1t_h = (f16*)(ws + 0 * MB);
    f16* W1t_l = (f16*)(ws + 2 * MB);
    f16* W2t_h = (f16*)(ws + 4 * MB);
    f16* W2t_l = (f16*)(ws + 6 * MB);
    f16* Hh    = (f16*)(ws + 8 * MB);
    f16* Hl    = (f16*)(ws + 12 * MB);
    unsigned char* mb = (unsigned char*)(ws + 16 * MB);
    float* part1 = (float*)(ws + 20 * MB);
    float* part2 = (float*)(ws + 36 * MB);
    float* inv_s = (float*)(ws + 38 * MB);

    k_prep<<<dim3(4, 64), 256, 0, stream>>>(W1, W1t_h, W1t_l, 4096, 256, 6);
    k_prep<<<dim3(64, 4), 256, 0, stream>>>(W2, W2t_h, W2t_l, 256, 4096, 6);
    k_gemm1f<<<dim3(128, 4, 2), 256, 0, stream>>>(x, W1t_h, W1t_l, mb, part1);
    k_hsplit<<<1024, 256, 0, stream>>>(part1, b1, Hh, Hl);
    k_gemm2<false><<<dim3(128, 64), 256, 0, stream>>>(
        Hh, Hl, W2t_h, W2t_l, b2, (const unsigned*)mb, out, (f16*)0, part2);
    k_rowinv<<<32, 256, 0, stream>>>(part2, inv_s);
    k_scale<<<32768, 256, 0, stream>>>(out, inv_s);
  }
}

// Round 6
// 254.482 us; speedup vs baseline: 1.0332x; 1.0332x over previous
//
#include <hip/hip_runtime.h>

typedef _Float16 f16;
typedef _Float16 f16x8 __attribute__((ext_vector_type(8)));
typedef float f32x4 __attribute__((ext_vector_type(4)));

#define MFMA16(a,b,c) __builtin_amdgcn_mfma_f32_16x16x32_f16((a),(b),(c),0,0,0)

__device__ __forceinline__ void gload16(const void* g, void* l) {
  __builtin_amdgcn_global_load_lds(
      (const __attribute__((address_space(1))) void*)g,
      (__attribute__((address_space(3))) void*)l, 16, 0, 0);
}

// swizzled f16 offset within a [rows][32 k] tile; c = 8-f16 chunk (0..3)
__device__ __forceinline__ int swz(int r, int c) {
  return r * 32 + ((c ^ (r & 3)) << 3);
}

// RTN split: v = hi + lo with hi = RTN f16
__device__ __forceinline__ void split8n(const f32x4 v0, const f32x4 v1,
                                        f16x8& hv, f16x8& lv) {
#pragma unroll
  for (int j = 0; j < 4; ++j) {
    f16 h0 = (f16)v0[j]; hv[j] = h0; lv[j] = (f16)(v0[j] - (float)h0);
    f16 h1 = (f16)v1[j]; hv[j + 4] = h1; lv[j + 4] = (f16)(v1[j] - (float)h1);
  }
}

// ---------- prep: f32 in[R][C] -> tiled+swizzled fp16 hi/lo tiles ----------
// input is [R = k][C = n]; tile rows are n, TR = 1<<trShift; tileIdx = (n>>trShift)*(R/32) + k/32
__global__ __launch_bounds__(256) void k_prep(const float* __restrict__ in,
                                              f16* __restrict__ oh, f16* __restrict__ ol,
                                              int R, int C, int trShift) {
  __shared__ float t[64][65];
  int c0 = blockIdx.x * 64, r0 = blockIdx.y * 64;
  int tid = threadIdx.x;
#pragma unroll
  for (int i = 0; i < 16; ++i) {
    int idx = tid + i * 256;
    int r = idx >> 6, c = idx & 63;
    t[r][c] = in[(size_t)(r0 + r) * C + (c0 + c)];
  }
  __syncthreads();
  int ktiles = R >> 5;
  int TRm1 = (1 << trShift) - 1;
#pragma unroll
  for (int w = 0; w < 2; ++w) {
    int idx = tid + w * 256;
    int nn = idx >> 3, cc8 = idx & 7;
    f32x4 v0, v1;
#pragma unroll
    for (int j = 0; j < 4; ++j) v0[j] = t[cc8 * 8 + j][nn];
#pragma unroll
    for (int j = 0; j < 4; ++j) v1[j] = t[cc8 * 8 + 4 + j][nn];
    f16x8 hv, lv;
    split8n(v0, v1, hv, lv);
    int gn = c0 + nn, gk = r0 + cc8 * 8;
    size_t tileIdx = (size_t)(gn >> trShift) * ktiles + (gk >> 5);
    size_t off = (tileIdx << (trShift + 5)) + ((size_t)(gn & TRm1) << 5) +
                 (((cc8 & 3) ^ (gn & 3)) << 3);
    *(f16x8*)&oh[off] = hv;
    *(f16x8*)&ol[off] = lv;
  }
}

// ---------- xprep: X f32 -> tiled+swizzled fp16 hi/lo (TR=64) + mask ----------
__global__ __launch_bounds__(256) void k_xprep(const float* __restrict__ X,
                                               f16* __restrict__ Xh, f16* __restrict__ Xl,
                                               unsigned short* __restrict__ mb2) {
  int m0 = blockIdx.x * 64, kb0 = blockIdx.y * 64;
  int tid = threadIdx.x;
  int r = tid >> 2, c0 = (tid & 3) * 16;
  const float* p = X + (size_t)(m0 + r) * 4096 + kb0 + c0;
  f32x4 a0 = *(const f32x4*)p, a1 = *(const f32x4*)(p + 4);
  f32x4 a2 = *(const f32x4*)(p + 8), a3 = *(const f32x4*)(p + 12);
  f16x8 h0, l0, h1, l1;
  split8n(a0, a1, h0, l0);
  split8n(a2, a3, h1, l1);
  int gk = kb0 + c0;
  int kt = gk >> 5, cc = (gk & 31) >> 3;
  size_t tile = (size_t)blockIdx.x * 128 + kt;
  size_t o0 = tile * 2048 + swz(r, cc);
  size_t o1 = tile * 2048 + swz(r, cc + 1);
  *(f16x8*)&Xh[o0] = h0; *(f16x8*)&Xh[o1] = h1;
  *(f16x8*)&Xl[o0] = l0; *(f16x8*)&Xl[o1] = l1;
  unsigned m = 0;
#pragma unroll
  for (int j = 0; j < 4; ++j) {
    if (a0[j] != 0.f) m |= 1u << j;
    if (a1[j] != 0.f) m |= 1u << (4 + j);
    if (a2[j] != 0.f) m |= 1u << (8 + j);
    if (a3[j] != 0.f) m |= 1u << (12 + j);
  }
  mb2[((size_t)(m0 + r) * 512 + (gk >> 3)) >> 1] = (unsigned short)m;
}

// ---------- GEMM1 pipelined: all-gload staging, counted vmcnt ----------
// BM=64, BN=128, BK=32; A and B both 3-buffered, distance-2 prefetch
__global__ __launch_bounds__(256, 2) void k_gemm1p(
    const f16* __restrict__ Xh, const f16* __restrict__ Xl,
    const f16* __restrict__ Bht, const f16* __restrict__ Blt,
    float* __restrict__ partials) {
  __shared__ f16 smA[3][4096];   // [buf][Ah 0..2048 | Al 2048..4096]
  __shared__ f16 smB[3][8192];   // [buf][Bh 0..4096 | Bl 4096..8192]
  int bx = blockIdx.x, nb = blockIdx.y, kc = blockIdx.z;
  int tid = threadIdx.x;
  int wv = tid >> 6, ln = tid & 63, lr = ln & 15, lg = ln >> 4;
  int wr = wv >> 1, wc = wv & 1;
  const int NS = 64;
  size_t a0 = ((size_t)bx * 128 + (size_t)kc * 64) * 2048;
  size_t b0 = ((size_t)nb * 128 + (size_t)kc * 64) * 4096;

  auto issueTile = [&](int s, int buf) {
    const f16* ah = Xh + a0 + (size_t)s * 2048 + (size_t)tid * 8;
    const f16* al = Xl + a0 + (size_t)s * 2048 + (size_t)tid * 8;
    gload16(ah, &smA[buf][wv * 512]);
    gload16(al, &smA[buf][2048 + wv * 512]);
    const f16* bh = Bht + b0 + (size_t)s * 4096 + (size_t)tid * 8;
    const f16* bl = Blt + b0 + (size_t)s * 4096 + (size_t)tid * 8;
    gload16(bh, &smB[buf][wv * 512]);
    gload16(bh + 2048, &smB[buf][2048 + wv * 512]);
    gload16(bl, &smB[buf][4096 + wv * 512]);
    gload16(bl + 2048, &smB[buf][6144 + wv * 512]);
  };

  f32x4 acc[2][4] = {};

  issueTile(0, 0);
  issueTile(1, 1);
  asm volatile("s_waitcnt vmcnt(6)" ::: "memory");
  __builtin_amdgcn_s_barrier();

  int cb = 0;
  for (int s = 0; s < NS; ++s) {
    if (s + 2 < NS) {
      int pb = cb + 2; if (pb >= 3) pb -= 3;
      issueTile(s + 2, pb);
    }
    const f16* ab = &smA[cb][0];
    const f16* bb = &smB[cb][0];
    f16x8 fah[2], fal[2], fbh[4], fbl[4];
#pragma unroll
    for (int fi = 0; fi < 2; ++fi) {
      int r = wr * 32 + fi * 16 + lr;
      fah[fi] = *(const f16x8*)(ab + swz(r, lg));
      fal[fi] = *(const f16x8*)(ab + 2048 + swz(r, lg));
    }
#pragma unroll
    for (int fj = 0; fj < 4; ++fj) {
      int c = wc * 64 + fj * 16 + lr;
      fbh[fj] = *(const f16x8*)(bb + swz(c, lg));
      fbl[fj] = *(const f16x8*)(bb + 4096 + swz(c, lg));
    }
#pragma unroll
    for (int fi = 0; fi < 2; ++fi)
#pragma unroll
      for (int fj = 0; fj < 4; ++fj) {
        acc[fi][fj] = MFMA16(fah[fi], fbh[fj], acc[fi][fj]);
        acc[fi][fj] = MFMA16(fah[fi], fbl[fj], acc[fi][fj]);
        acc[fi][fj] = MFMA16(fal[fi], fbh[fj], acc[fi][fj]);
      }
    if (s + 2 < NS)
      asm volatile("s_waitcnt vmcnt(6)" ::: "memory");
    else
      asm volatile("s_waitcnt vmcnt(0)" ::: "memory");
    __builtin_amdgcn_s_barrier();
    cb = cb + 1; if (cb >= 3) cb -= 3;
  }

  float* pout = partials + (size_t)kc * 8192 * 256;
#pragma unroll
  for (int fi = 0; fi < 2; ++fi)
#pragma unroll
    for (int fj = 0; fj < 4; ++fj)
#pragma unroll
      for (int r = 0; r < 4; ++r) {
        int row = bx * 64 + wr * 32 + fi * 16 + lg * 4 + r;
        int col = nb * 128 + wc * 64 + fj * 16 + lr;
        pout[(size_t)row * 256 + col] = acc[fi][fj][r];
      }
}

// ---------- reduce split-K + bias + relu + split -> tiled H hi/lo (TR=128) ----------
__global__ __launch_bounds__(256) void k_hsplit(const float* __restrict__ p,
                                                const float* __restrict__ b1,
                                                f16* __restrict__ Hh,
                                                f16* __restrict__ Hl) {
  int g = blockIdx.x * 256 + threadIdx.x;
  int r = g >> 5, c = g & 31;
  const float* p0 = p + (size_t)r * 256 + c * 8;
  const float* p1 = p0 + (size_t)8192 * 256;
  f32x4 a0 = *(const f32x4*)p0, a1 = *(const f32x4*)(p0 + 4);
  f32x4 d0 = *(const f32x4*)p1, d1 = *(const f32x4*)(p1 + 4);
  f32x4 bb0 = *(const f32x4*)(b1 + c * 8), bb1 = *(const f32x4*)(b1 + c * 8 + 4);
  f32x4 v0, v1;
#pragma unroll
  for (int j = 0; j < 4; ++j) {
    float v = a0[j] + d0[j] + bb0[j];
    v0[j] = v > 0.f ? v : 0.f;
    float w = a1[j] + d1[j] + bb1[j];
    v1[j] = w > 0.f ? w : 0.f;
  }
  f16x8 hv, lv;
  split8n(v0, v1, hv, lv);
  size_t tileIdx = (size_t)(r >> 7) * 8 + (c >> 2);
  size_t off = tileIdx * 4096 + ((size_t)(r & 127) << 5) + (((c & 3) ^ (r & 3)) << 3);
  *(f16x8*)&Hh[off] = hv;
  *(f16x8*)&Hl[off] = lv;
}

// ---------- GEMM2: 128x128 tile, F = H @ W2 + b2, masked f16 store + row sums ----------
__global__ __launch_bounds__(256, 2) void k_gemm2b(
    const f16* __restrict__ At_h, const f16* __restrict__ At_l,
    const f16* __restrict__ Bt_h, const f16* __restrict__ Bt_l,
    const float* __restrict__ b2, const unsigned* __restrict__ maskw,
    f16* __restrict__ fout, float* __restrict__ partials) {
  __shared__ f16 smA[2][2][4096];  // [buf][h/l][128 rows x 32 k]
  __shared__ f16 smB[2][2][4096];
  __shared__ unsigned mlds[128][4];
  __shared__ float rsum[128][2];
  int bx = blockIdx.x, by = blockIdx.y;
  int m0 = bx * 128, n0 = by * 128;
  int tid = threadIdx.x;
  int wv = tid >> 6, ln = tid & 63, lr = ln & 15, lg = ln >> 4;
  int wr = wv >> 1, wc = wv & 1;
#pragma unroll
  for (int i = 0; i < 2; ++i) {
    int idx = tid + i * 256;
    mlds[idx >> 2][idx & 3] =
        maskw[(size_t)(m0 + (idx >> 2)) * 128 + by * 4 + (idx & 3)];
  }
  size_t at0 = (size_t)bx * 8 * 4096;
  size_t bt0 = (size_t)by * 8 * 4096;

  auto stage = [&](int s, int buf) {
#pragma unroll
    for (int w = 0; w < 2; ++w) {
      size_t o = (size_t)(w * 4 + wv) * 512 + (size_t)ln * 8;
      gload16(At_h + at0 + (size_t)s * 4096 + o, &smA[buf][0][(w * 4 + wv) * 512]);
      gload16(At_l + at0 + (size_t)s * 4096 + o, &smA[buf][1][(w * 4 + wv) * 512]);
      gload16(Bt_h + bt0 + (size_t)s * 4096 + o, &smB[buf][0][(w * 4 + wv) * 512]);
      gload16(Bt_l + bt0 + (size_t)s * 4096 + o, &smB[buf][1][(w * 4 + wv) * 512]);
    }
  };

  f32x4 acc[4][4] = {};
  stage(0, 0);
  __syncthreads();
  int cur = 0;
  for (int s = 0; s < 8; ++s) {
    if (s + 1 < 8) stage(s + 1, cur ^ 1);
    f16x8 fah[4], fal[4], fbh[4], fbl[4];
#pragma unroll
    for (int f = 0; f < 4; ++f) {
      int r = wr * 64 + f * 16 + lr;
      fah[f] = *(const f16x8*)&smA[cur][0][swz(r, lg)];
      fal[f] = *(const f16x8*)&smA[cur][1][swz(r, lg)];
      int c = wc * 64 + f * 16 + lr;
      fbh[f] = *(const f16x8*)&smB[cur][0][swz(c, lg)];
      fbl[f] = *(const f16x8*)&smB[cur][1][swz(c, lg)];
    }
#pragma unroll
    for (int fi = 0; fi < 4; ++fi)
#pragma unroll
      for (int fj = 0; fj < 4; ++fj) {
        acc[fi][fj] = MFMA16(fah[fi], fbh[fj], acc[fi][fj]);
        acc[fi][fj] = MFMA16(fah[fi], fbl[fj], acc[fi][fj]);
        acc[fi][fj] = MFMA16(fal[fi], fbh[fj], acc[fi][fj]);
      }
    __syncthreads();
    cur ^= 1;
  }

  float rp[4][4] = {};
#pragma unroll
  for (int fi = 0; fi < 4; ++fi)
#pragma unroll
    for (int fj = 0; fj < 4; ++fj)
#pragma unroll
      for (int q = 0; q < 4; ++q) {
        int row = wr * 64 + fi * 16 + lg * 4 + q;
        int col = wc * 64 + fj * 16 + lr;
        float v = acc[fi][fj][q] + b2[n0 + col];
        unsigned wd = mlds[row][col >> 5];
        float mv = ((wd >> (col & 31)) & 1u) ? v : 0.f;
        fout[(size_t)(m0 + row) * 4096 + (n0 + col)] = (f16)mv;
        rp[fi][q] += mv;
      }
#pragma unroll
  for (int fi = 0; fi < 4; ++fi)
#pragma unroll
    for (int q = 0; q < 4; ++q) {
      float sv = rp[fi][q];
      sv += __shfl_xor(sv, 1);
      sv += __shfl_xor(sv, 2);
      sv += __shfl_xor(sv, 4);
      sv += __shfl_xor(sv, 8);
      if (lr == 0) rsum[wr * 64 + fi * 16 + lg * 4 + q][wc] = sv;
    }
  __syncthreads();
  if (tid < 128)
    partials[(size_t)(m0 + tid) * 32 + by] = rsum[tid][0] + rsum[tid][1];
}

// ---------- per-row inverse of masked sum ----------
__global__ __launch_bounds__(256) void k_rowinv(const float* __restrict__ partials,
                                                float* __restrict__ inv) {
  int r = blockIdx.x * 256 + threadIdx.x;
  if (r < 8192) {
    float s = 0.f;
#pragma unroll 4
    for (int i = 0; i < 32; ++i) s += partials[(size_t)r * 32 + i];
    float ss = (s == 0.f) ? 1.f : s;
    inv[r] = 1.f / ss;
  }
}

// ---------- scale: f16 f * inv -> f32 out ----------
__global__ __launch_bounds__(256) void k_scale16(const f16* __restrict__ f,
                                                 const float* __restrict__ inv,
                                                 float* __restrict__ out) {
  int v = blockIdx.x * 256 + threadIdx.x;
  float iv = inv[v >> 9];
  f16x8 d = *(const f16x8*)(f + (size_t)v * 8);
  f32x4 o0, o1;
#pragma unroll
  for (int j = 0; j < 4; ++j) {
    o0[j] = (float)d[j] * iv;
    o1[j] = (float)d[4 + j] * iv;
  }
  *(f32x4*)(out + (size_t)v * 8) = o0;
  *(f32x4*)(out + (size_t)v * 8 + 4) = o1;
}

extern "C" void kernel_launch(void* const* d_in, const int* in_sizes, int n_in,
                              void* d_out, int out_size, void* d_ws, size_t ws_size,
                              hipStream_t stream) {
  const float* x  = (const float*)d_in[0];
  const float* W1 = (const float*)d_in[1];
  const float* b1 = (const float*)d_in[2];
  const float* W2 = (const float*)d_in[3];
  const float* b2 = (const float*)d_in[4];
  float* out = (float*)d_out;
  char* ws = (char*)d_ws;

  const size_t MB = (size_t)1 << 20;
  f16* W1t_h = (f16*)(ws + 0 * MB);    // 2 MB, TR=128 tiles
  f16* W1t_l = (f16*)(ws + 2 * MB);
  f16* W2t_h = (f16*)(ws + 4 * MB);    // 2 MB, TR=128 tiles
  f16* W2t_l = (f16*)(ws + 6 * MB);
  f16* Xh    = (f16*)(ws + 8 * MB);    // 64 MB, TR=64 tiles
  f16* Xl    = (f16*)(ws + 72 * MB);   // 64 MB
  f16* Hh    = (f16*)(ws + 136 * MB);  // 4 MB, TR=128 tiles
  f16* Hl    = (f16*)(ws + 140 * MB);
  unsigned char* mb = (unsigned char*)(ws + 144 * MB);  // 4 MB
  float* part1 = (float*)(ws + 148 * MB);  // 16 MB (2 x 8 MB split-K)
  float* part2 = (float*)(ws + 164 * MB);  // 1 MB [8192][32]
  float* inv_s = (float*)(ws + 166 * MB);  // 32 KB
  f16* fbuf = Xh;  // 64 MB, X tiles dead after gemm1

  // W1 [4096 k][256 n] -> TR=128 tiles; W2 [256 k][4096 n] -> TR=128 tiles
  k_prep<<<dim3(4, 64), 256, 0, stream>>>(W1, W1t_h, W1t_l, 4096, 256, 7);
  k_prep<<<dim3(64, 4), 256, 0, stream>>>(W2, W2t_h, W2t_l, 256, 4096, 7);
  k_xprep<<<dim3(128, 64), 256, 0, stream>>>(x, Xh, Xl, (unsigned short*)mb);
  k_gemm1p<<<dim3(128, 2, 2), 256, 0, stream>>>(Xh, Xl, W1t_h, W1t_l, part1);
  k_hsplit<<<1024, 256, 0, stream>>>(part1, b1, Hh, Hl);
  k_gemm2b<<<dim3(64, 32), 256, 0, stream>>>(Hh, Hl, W2t_h, W2t_l, b2,
                                             (const unsigned*)mb, fbuf, part2);
  k_rowinv<<<32, 256, 0, stream>>>(part2, inv_s);
  k_scale16<<<16384, 256, 0, stream>>>(fbuf, inv_s, out);
}

// Round 7
// 215.195 us; speedup vs baseline: 1.2218x; 1.1826x over previous
//
#include <hip/hip_runtime.h>

typedef _Float16 f16;
typedef _Float16 f16x8 __attribute__((ext_vector_type(8)));
typedef float f32x4 __attribute__((ext_vector_type(4)));

#define MFMA16(a,b,c) __builtin_amdgcn_mfma_f32_16x16x32_f16((a),(b),(c),0,0,0)

__device__ __forceinline__ void gload16(const void* g, void* l) {
  __builtin_amdgcn_global_load_lds(
      (const __attribute__((address_space(1))) void*)g,
      (__attribute__((address_space(3))) void*)l, 16, 0, 0);
}

// swizzled f16 offset within a [rows][32 k] tile; c = 8-f16 chunk (0..3)
__device__ __forceinline__ int swz(int r, int c) {
  return r * 32 + ((c ^ (r & 3)) << 3);
}

// RTN split: v = hi + lo with hi = RTN f16
__device__ __forceinline__ void split8n(const f32x4 v0, const f32x4 v1,
                                        f16x8& hv, f16x8& lv) {
#pragma unroll
  for (int j = 0; j < 4; ++j) {
    f16 h0 = (f16)v0[j]; hv[j] = h0; lv[j] = (f16)(v0[j] - (float)h0);
    f16 h1 = (f16)v1[j]; hv[j + 4] = h1; lv[j + 4] = (f16)(v1[j] - (float)h1);
  }
}

// ---------- prep: f32 in[R][C] -> tiled+swizzled fp16 hi/lo tiles ----------
// input is [R = k][C = n]; TR = 1<<trShift; tileIdx = (n>>trShift)*(R/32) + k/32
__global__ __launch_bounds__(256) void k_prep(const float* __restrict__ in,
                                              f16* __restrict__ oh, f16* __restrict__ ol,
                                              int R, int C, int trShift) {
  __shared__ float t[64][65];
  int c0 = blockIdx.x * 64, r0 = blockIdx.y * 64;
  int tid = threadIdx.x;
#pragma unroll
  for (int i = 0; i < 16; ++i) {
    int idx = tid + i * 256;
    int r = idx >> 6, c = idx & 63;
    t[r][c] = in[(size_t)(r0 + r) * C + (c0 + c)];
  }
  __syncthreads();
  int ktiles = R >> 5;
  int TRm1 = (1 << trShift) - 1;
#pragma unroll
  for (int w = 0; w < 2; ++w) {
    int idx = tid + w * 256;
    int nn = idx >> 3, cc8 = idx & 7;
    f32x4 v0, v1;
#pragma unroll
    for (int j = 0; j < 4; ++j) v0[j] = t[cc8 * 8 + j][nn];
#pragma unroll
    for (int j = 0; j < 4; ++j) v1[j] = t[cc8 * 8 + 4 + j][nn];
    f16x8 hv, lv;
    split8n(v0, v1, hv, lv);
    int gn = c0 + nn, gk = r0 + cc8 * 8;
    size_t tileIdx = (size_t)(gn >> trShift) * ktiles + (gk >> 5);
    size_t off = (tileIdx << (trShift + 5)) + ((size_t)(gn & TRm1) << 5) +
                 (((cc8 & 3) ^ (gn & 3)) << 3);
    *(f16x8*)&oh[off] = hv;
    *(f16x8*)&ol[off] = lv;
  }
}

// ---------- GEMM1 v3: 128x128 tile, X f32 read + in-loop RTN split, split-K=4 ----------
// grid (64 bx, 2 nb, 4 kc); A = X reg-staged -> LDS; B = W1 TR=128 tiles via gload
__global__ __launch_bounds__(256, 2) void k_g1(
    const float* __restrict__ X, const f16* __restrict__ Bht,
    const f16* __restrict__ Blt, unsigned short* __restrict__ mb2,
    float* __restrict__ partials) {
  __shared__ f16 smA[2][2][4096];  // [buf][h/l][128 m x 32 k]
  __shared__ f16 smB[2][2][4096];  // [buf][h/l][128 n x 32 k]
  int bx = blockIdx.x, nb = blockIdx.y, kc = blockIdx.z;
  int tid = threadIdx.x;
  int wv = tid >> 6, ln = tid & 63, lr = ln & 15, lg = ln >> 4;
  int wr = wv >> 1, wc = wv & 1;
  const int NS = 32;  // 1024 k per block / 32
  int m0 = bx * 128, kb0 = kc * 1024;
  int arow = tid >> 1, akc = tid & 1;  // each thread: 1 row, 16 consecutive k
  const float* xp = X + (size_t)(m0 + arow) * 4096 + kb0 + akc * 16;
  size_t bt0 = ((size_t)nb * 128 + (size_t)kc * 32) * 4096;
  bool domask = (nb == 0);
  int wo0 = swz(arow, 2 * akc);
  int wo1 = swz(arow, 2 * akc + 1);

  auto stageB = [&](int s, int buf) {
#pragma unroll
    for (int w = 0; w < 2; ++w) {
      size_t o = (size_t)(w * 4 + wv) * 512 + (size_t)ln * 8;
      gload16(Bht + bt0 + (size_t)s * 4096 + o, &smB[buf][0][(w * 4 + wv) * 512]);
      gload16(Blt + bt0 + (size_t)s * 4096 + o, &smB[buf][1][(w * 4 + wv) * 512]);
    }
  };
  auto commitA = [&](f32x4 a0, f32x4 a1, f32x4 a2, f32x4 a3, int buf, int s) {
    f16x8 h0, l0, h1, l1;
    split8n(a0, a1, h0, l0);
    split8n(a2, a3, h1, l1);
    *(f16x8*)&smA[buf][0][wo0] = h0;
    *(f16x8*)&smA[buf][0][wo1] = h1;
    *(f16x8*)&smA[buf][1][wo0] = l0;
    *(f16x8*)&smA[buf][1][wo1] = l1;
    if (domask) {
      unsigned m = 0;
#pragma unroll
      for (int j = 0; j < 4; ++j) {
        if (a0[j] != 0.f) m |= 1u << j;
        if (a1[j] != 0.f) m |= 1u << (4 + j);
        if (a2[j] != 0.f) m |= 1u << (8 + j);
        if (a3[j] != 0.f) m |= 1u << (12 + j);
      }
      int gk = kb0 + s * 32 + akc * 16;
      mb2[((size_t)(m0 + arow) * 512 + (gk >> 3)) >> 1] = (unsigned short)m;
    }
  };

  f32x4 acc[4][4] = {};

  // prologue
  stageB(0, 0);
  {
    f32x4 a0 = *(const f32x4*)xp, a1 = *(const f32x4*)(xp + 4);
    f32x4 a2 = *(const f32x4*)(xp + 8), a3 = *(const f32x4*)(xp + 12);
    commitA(a0, a1, a2, a3, 0, 0);
  }
  __syncthreads();

  int cur = 0;
  for (int s = 0; s < NS; ++s) {
    f32x4 a0, a1, a2, a3;
    bool more = (s + 1) < NS;
    if (more) {
      const float* xn = xp + (s + 1) * 32;
      a0 = *(const f32x4*)xn; a1 = *(const f32x4*)(xn + 4);
      a2 = *(const f32x4*)(xn + 8); a3 = *(const f32x4*)(xn + 12);
      stageB(s + 1, cur ^ 1);
    }
    f16x8 fah[4], fal[4], fbh[4], fbl[4];
#pragma unroll
    for (int f = 0; f < 4; ++f) {
      int r = wr * 64 + f * 16 + lr;
      fah[f] = *(const f16x8*)&smA[cur][0][swz(r, lg)];
      fal[f] = *(const f16x8*)&smA[cur][1][swz(r, lg)];
      int c = wc * 64 + f * 16 + lr;
      fbh[f] = *(const f16x8*)&smB[cur][0][swz(c, lg)];
      fbl[f] = *(const f16x8*)&smB[cur][1][swz(c, lg)];
    }
#pragma unroll
    for (int fi = 0; fi < 4; ++fi)
#pragma unroll
      for (int fj = 0; fj < 4; ++fj) {
        acc[fi][fj] = MFMA16(fah[fi], fbh[fj], acc[fi][fj]);
        acc[fi][fj] = MFMA16(fah[fi], fbl[fj], acc[fi][fj]);
        acc[fi][fj] = MFMA16(fal[fi], fbh[fj], acc[fi][fj]);
      }
    if (more) commitA(a0, a1, a2, a3, cur ^ 1, s + 1);
    __syncthreads();
    cur ^= 1;
  }

  float* pout = partials + (size_t)kc * 8192 * 256;
#pragma unroll
  for (int fi = 0; fi < 4; ++fi)
#pragma unroll
    for (int fj = 0; fj < 4; ++fj)
#pragma unroll
      for (int q = 0; q < 4; ++q) {
        int row = m0 + wr * 64 + fi * 16 + lg * 4 + q;
        int col = nb * 128 + wc * 64 + fj * 16 + lr;
        pout[(size_t)row * 256 + col] = acc[fi][fj][q];
      }
}

// ---------- reduce split-K(4) + bias + relu + split -> tiled H hi/lo (TR=128) ----------
__global__ __launch_bounds__(256) void k_hsplit(const float* __restrict__ p,
                                                const float* __restrict__ b1,
                                                f16* __restrict__ Hh,
                                                f16* __restrict__ Hl) {
  int g = blockIdx.x * 256 + threadIdx.x;
  int r = g >> 5, c = g & 31;
  const size_t CH = (size_t)8192 * 256;
  const float* p0 = p + (size_t)r * 256 + c * 8;
  f32x4 s0 = *(const f32x4*)p0, s1 = *(const f32x4*)(p0 + 4);
#pragma unroll
  for (int q = 1; q < 4; ++q) {
    f32x4 d0 = *(const f32x4*)(p0 + q * CH), d1 = *(const f32x4*)(p0 + q * CH + 4);
#pragma unroll
    for (int j = 0; j < 4; ++j) { s0[j] += d0[j]; s1[j] += d1[j]; }
  }
  f32x4 bb0 = *(const f32x4*)(b1 + c * 8), bb1 = *(const f32x4*)(b1 + c * 8 + 4);
  f32x4 v0, v1;
#pragma unroll
  for (int j = 0; j < 4; ++j) {
    float v = s0[j] + bb0[j];
    v0[j] = v > 0.f ? v : 0.f;
    float w = s1[j] + bb1[j];
    v1[j] = w > 0.f ? w : 0.f;
  }
  f16x8 hv, lv;
  split8n(v0, v1, hv, lv);
  size_t tileIdx = (size_t)(r >> 7) * 8 + (c >> 2);
  size_t off = tileIdx * 4096 + ((size_t)(r & 127) << 5) + (((c & 3) ^ (r & 3)) << 3);
  *(f16x8*)&Hh[off] = hv;
  *(f16x8*)&Hl[off] = lv;
}

// ---------- GEMM2: 128x128 tile, F = H @ W2 + b2, masked f16 store + row sums ----------
__global__ __launch_bounds__(256, 2) void k_gemm2b(
    const f16* __restrict__ At_h, const f16* __restrict__ At_l,
    const f16* __restrict__ Bt_h, const f16* __restrict__ Bt_l,
    const float* __restrict__ b2, const unsigned* __restrict__ maskw,
    f16* __restrict__ fout, float* __restrict__ partials) {
  __shared__ f16 smA[2][2][4096];
  __shared__ f16 smB[2][2][4096];
  __shared__ unsigned mlds[128][4];
  __shared__ float rsum[128][2];
  int bx = blockIdx.x, by = blockIdx.y;
  int m0 = bx * 128, n0 = by * 128;
  int tid = threadIdx.x;
  int wv = tid >> 6, ln = tid & 63, lr = ln & 15, lg = ln >> 4;
  int wr = wv >> 1, wc = wv & 1;
#pragma unroll
  for (int i = 0; i < 2; ++i) {
    int idx = tid + i * 256;
    mlds[idx >> 2][idx & 3] =
        maskw[(size_t)(m0 + (idx >> 2)) * 128 + by * 4 + (idx & 3)];
  }
  size_t at0 = (size_t)bx * 8 * 4096;
  size_t bt0 = (size_t)by * 8 * 4096;

  auto stage = [&](int s, int buf) {
#pragma unroll
    for (int w = 0; w < 2; ++w) {
      size_t o = (size_t)(w * 4 + wv) * 512 + (size_t)ln * 8;
      gload16(At_h + at0 + (size_t)s * 4096 + o, &smA[buf][0][(w * 4 + wv) * 512]);
      gload16(At_l + at0 + (size_t)s * 4096 + o, &smA[buf][1][(w * 4 + wv) * 512]);
      gload16(Bt_h + bt0 + (size_t)s * 4096 + o, &smB[buf][0][(w * 4 + wv) * 512]);
      gload16(Bt_l + bt0 + (size_t)s * 4096 + o, &smB[buf][1][(w * 4 + wv) * 512]);
    }
  };

  f32x4 acc[4][4] = {};
  stage(0, 0);
  __syncthreads();
  int cur = 0;
  for (int s = 0; s < 8; ++s) {
    if (s + 1 < 8) stage(s + 1, cur ^ 1);
    f16x8 fah[4], fal[4], fbh[4], fbl[4];
#pragma unroll
    for (int f = 0; f < 4; ++f) {
      int r = wr * 64 + f * 16 + lr;
      fah[f] = *(const f16x8*)&smA[cur][0][swz(r, lg)];
      fal[f] = *(const f16x8*)&smA[cur][1][swz(r, lg)];
      int c = wc * 64 + f * 16 + lr;
      fbh[f] = *(const f16x8*)&smB[cur][0][swz(c, lg)];
      fbl[f] = *(const f16x8*)&smB[cur][1][swz(c, lg)];
    }
#pragma unroll
    for (int fi = 0; fi < 4; ++fi)
#pragma unroll
      for (int fj = 0; fj < 4; ++fj) {
        acc[fi][fj] = MFMA16(fah[fi], fbh[fj], acc[fi][fj]);
        acc[fi][fj] = MFMA16(fah[fi], fbl[fj], acc[fi][fj]);
        acc[fi][fj] = MFMA16(fal[fi], fbh[fj], acc[fi][fj]);
      }
    __syncthreads();
    cur ^= 1;
  }

  float rp[4][4] = {};
#pragma unroll
  for (int fi = 0; fi < 4; ++fi)
#pragma unroll
    for (int fj = 0; fj < 4; ++fj)
#pragma unroll
      for (int q = 0; q < 4; ++q) {
        int row = wr * 64 + fi * 16 + lg * 4 + q;
        int col = wc * 64 + fj * 16 + lr;
        float v = acc[fi][fj][q] + b2[n0 + col];
        unsigned wd = mlds[row][col >> 5];
        float mv = ((wd >> (col & 31)) & 1u) ? v : 0.f;
        fout[(size_t)(m0 + row) * 4096 + (n0 + col)] = (f16)mv;
        rp[fi][q] += mv;
      }
#pragma unroll
  for (int fi = 0; fi < 4; ++fi)
#pragma unroll
    for (int q = 0; q < 4; ++q) {
      float sv = rp[fi][q];
      sv += __shfl_xor(sv, 1);
      sv += __shfl_xor(sv, 2);
      sv += __shfl_xor(sv, 4);
      sv += __shfl_xor(sv, 8);
      if (lr == 0) rsum[wr * 64 + fi * 16 + lg * 4 + q][wc] = sv;
    }
  __syncthreads();
  if (tid < 128)
    partials[(size_t)(m0 + tid) * 32 + by] = rsum[tid][0] + rsum[tid][1];
}

// ---------- per-row inverse of masked sum ----------
__global__ __launch_bounds__(256) void k_rowinv(const float* __restrict__ partials,
                                                float* __restrict__ inv) {
  int r = blockIdx.x * 256 + threadIdx.x;
  if (r < 8192) {
    float s = 0.f;
#pragma unroll 4
    for (int i = 0; i < 32; ++i) s += partials[(size_t)r * 32 + i];
    float ss = (s == 0.f) ? 1.f : s;
    inv[r] = 1.f / ss;
  }
}

// ---------- scale: f16 f * inv -> f32 out ----------
__global__ __launch_bounds__(256) void k_scale16(const f16* __restrict__ f,
                                                 const float* __restrict__ inv,
                                                 float* __restrict__ out) {
  int v = blockIdx.x * 256 + threadIdx.x;
  float iv = inv[v >> 9];
  f16x8 d = *(const f16x8*)(f + (size_t)v * 8);
  f32x4 o0, o1;
#pragma unroll
  for (int j = 0; j < 4; ++j) {
    o0[j] = (float)d[j] * iv;
    o1[j] = (float)d[4 + j] * iv;
  }
  *(f32x4*)(out + (size_t)v * 8) = o0;
  *(f32x4*)(out + (size_t)v * 8 + 4) = o1;
}

extern "C" void kernel_launch(void* const* d_in, const int* in_sizes, int n_in,
                              void* d_out, int out_size, void* d_ws, size_t ws_size,
                              hipStream_t stream) {
  const float* x  = (const float*)d_in[0];
  const float* W1 = (const float*)d_in[1];
  const float* b1 = (const float*)d_in[2];
  const float* W2 = (const float*)d_in[3];
  const float* b2 = (const float*)d_in[4];
  float* out = (float*)d_out;
  char* ws = (char*)d_ws;

  const size_t MB = (size_t)1 << 20;
  f16* W1t_h = (f16*)(ws + 0 * MB);    // 2 MB, TR=128 tiles
  f16* W1t_l = (f16*)(ws + 2 * MB);
  f16* W2t_h = (f16*)(ws + 4 * MB);    // 2 MB, TR=128 tiles
  f16* W2t_l = (f16*)(ws + 6 * MB);
  f16* Hh    = (f16*)(ws + 8 * MB);    // 4 MB, TR=128 tiles
  f16* Hl    = (f16*)(ws + 12 * MB);
  unsigned char* mb = (unsigned char*)(ws + 16 * MB);  // 4 MB
  float* part1 = (float*)(ws + 20 * MB);   // 32 MB (4 x 8 MB split-K)
  float* part2 = (float*)(ws + 52 * MB);   // 1 MB [8192][32]
  float* inv_s = (float*)(ws + 53 * MB);   // 32 KB
  f16* fbuf    = (f16*)(ws + 54 * MB);     // 64 MB f16 f-buffer

  // W1 [4096 k][256 n] -> TR=128 tiles; W2 [256 k][4096 n] -> TR=128 tiles
  k_prep<<<dim3(4, 64), 256, 0, stream>>>(W1, W1t_h, W1t_l, 4096, 256, 7);
  k_prep<<<dim3(64, 4), 256, 0, stream>>>(W2, W2t_h, W2t_l, 256, 4096, 7);
  k_g1<<<dim3(64, 2, 4), 256, 0, stream>>>(x, W1t_h, W1t_l,
                                           (unsigned short*)mb, part1);
  k_hsplit<<<1024, 256, 0, stream>>>(part1, b1, Hh, Hl);
  k_gemm2b<<<dim3(64, 32), 256, 0, stream>>>(Hh, Hl, W2t_h, W2t_l, b2,
                                             (const unsigned*)mb, fbuf, part2);
  k_rowinv<<<32, 256, 0, stream>>>(part2, inv_s);
  k_scale16<<<16384, 256, 0, stream>>>(fbuf, inv_s, out);
}